// Round 6
// baseline (144.285 us; speedup 1.0000x reference)
//
#include <hip/hip_runtime.h>
#include <math.h>

#define TOKENS 32768
#define KCODES 8192
#define DIM 32
#define NCHUNK 16
#define CPC 512                    // codes per chunk (per screen block)
#define GSZ 128                    // codes per stored-min group
#define NGROUPS 64                 // KCODES / GSZ
#define RT_TOK 16                  // tokens per rescore block (1 per wave)
#define ZQ_ELEMS (TOKENS * DIM)
#define MARGIN 1e-3f               // screen-unit margin (>> 2*eps_screen)

typedef __attribute__((ext_vector_type(8))) short short8v;  // 8 bf16
typedef __attribute__((ext_vector_type(4))) float f32x4;

// round-to-nearest-even float bits -> bf16 bits
__device__ inline unsigned rne16(unsigned u) {
  return (u + 0x7FFFu + ((u >> 16) & 1u)) >> 16;
}

// ---------------------------------------------------------------------------
// prep: w = -l2_normalize(emb row) split into 2 bf16 terms, stored in
// MFMA-A-fragment-linear layout; plus per-row sum(e^2) (f64 accum, f32 out).
// ---------------------------------------------------------------------------
__global__ __launch_bounds__(256) void prep_codes(
    const float* __restrict__ emb, short* __restrict__ cA,
    short* __restrict__ cB, float* __restrict__ seArr) {
  int gid = blockIdx.x * 256 + threadIdx.x;  // 0..262143
  int code = gid >> 5;
  int k = gid & 31;
  float v = emb[gid];
  double dv = (double)v;
  double ds = dv * dv;
#pragma unroll
  for (int off = 16; off > 0; off >>= 1) ds += __shfl_xor(ds, off, 32);
  if (k == 0) seArr[code] = (float)ds;
  float r = 1.0f / sqrtf((float)ds + 1e-12f);
  float w = -v * r;
  unsigned ua = rne16(__float_as_uint(w));
  float fa = __uint_as_float(ua << 16);
  unsigned ub = rne16(__float_as_uint(w - fa));
  int tile = code >> 4;
  int lane = (code & 15) | ((k >> 3) << 4);
  int off = tile * 512 + lane * 8 + (k & 7);
  cA[off] = (short)ua;
  cB[off] = (short)ub;
}

// ---------------------------------------------------------------------------
// screen: 3-term MFMA of s = z . (-e_n) (raw z).  Block = 4 waves x 64
// tokens; grid = (128 token-blocks, 16 chunks).  No LDS, no barriers.
// Stores per-(group,token) min screen value; group = 128 codes.
// ---------------------------------------------------------------------------
__global__ __launch_bounds__(256) void screen_kernel(
    const float* __restrict__ hs, const short* __restrict__ cA,
    const short* __restrict__ cB, float* __restrict__ pgmin) {
  int tid = threadIdx.x;
  int l = tid & 63;
  int w = tid >> 6;
  int g = l >> 4;
  int c16 = l & 15;
  int gt0 = blockIdx.x * 16 + w * 4;  // first token-tile of this wave
  int chunk = blockIdx.y;

  // token-side B fragments: raw z, 2-term bf16 split
  short8v zA[4], zB[4];
#pragma unroll
  for (int tt = 0; tt < 4; tt++) {
    int tok = (gt0 + tt) * 16 + c16;
    const float4* hp4 = (const float4*)(hs + (size_t)tok * DIM + g * 8);
    float4 q0 = hp4[0];
    float4 q1 = hp4[1];
    float x[8] = {q0.x, q0.y, q0.z, q0.w, q1.x, q1.y, q1.z, q1.w};
#pragma unroll
    for (int j = 0; j < 8; j++) {
      unsigned ua = rne16(__float_as_uint(x[j]));
      float fa = __uint_as_float(ua << 16);
      unsigned ub = rne16(__float_as_uint(x[j] - fa));
      zA[tt][j] = (short)ua;
      zB[tt][j] = (short)ub;
    }
  }

  int tbase = chunk * (CPC / 16);  // 32 tiles per chunk

  for (int grp = 0; grp < CPC / GSZ; grp++) {  // 4 groups of 128 codes
    float gm[4] = {3.4e38f, 3.4e38f, 3.4e38f, 3.4e38f};
#pragma unroll
    for (int ct = 0; ct < GSZ / 16; ct++) {  // 8 code-tiles
      int tile = tbase + grp * (GSZ / 16) + ct;
      short8v aA = *((const short8v*)(cA + (size_t)tile * 512) + l);
      short8v aB = *((const short8v*)(cB + (size_t)tile * 512) + l);
#pragma unroll
      for (int tt = 0; tt < 4; tt++) {
        f32x4 acc = {};
        acc = __builtin_amdgcn_mfma_f32_16x16x32_bf16(aA, zA[tt], acc, 0, 0, 0);
        acc = __builtin_amdgcn_mfma_f32_16x16x32_bf16(aA, zB[tt], acc, 0, 0, 0);
        acc = __builtin_amdgcn_mfma_f32_16x16x32_bf16(aB, zA[tt], acc, 0, 0, 0);
        float m = fminf(fminf(acc[0], acc[1]), fminf(acc[2], acc[3]));
        gm[tt] = fminf(gm[tt], m);
      }
    }
    int gidx = (chunk * (CPC / GSZ) + grp);
#pragma unroll
    for (int tt = 0; tt < 4; tt++) {
      float v = gm[tt];
      v = fminf(v, __shfl_xor(v, 16));
      v = fminf(v, __shfl_xor(v, 32));
      if (l < 16) {
        int tok = (gt0 + tt) * 16 + c16;
        pgmin[(size_t)gidx * TOKENS + tok] = v;
      }
    }
  }
}

// ---------------------------------------------------------------------------
// rescore: block = 1024 threads = 16 waves = 16 tokens (one per wave).
// pgmin staged as [64 grp][16 tok] -> every global read is a full 64B line.
// All f32.  Candidate groups within MARGIN of min group-screen -> f32
// rescore; argmin via packed (monotone-f32-bits, idx) u64 min reduce
// (exact value order + smallest-index tie-break).  Fused z_q gather/
// normalize, index write, loss partial (per-block single atomic).
// ---------------------------------------------------------------------------
__global__ __launch_bounds__(1024) void rescore_kernel(
    const float* __restrict__ hs, const float* __restrict__ emb,
    const float* __restrict__ seArr, const float* __restrict__ pgmin,
    float* __restrict__ out, float* __restrict__ lossacc) {
  __shared__ float pg[NGROUPS][RT_TOK + 1];  // [grp][tok], padded (17: free)
  __shared__ float zsh[RT_TOK][DIM];
  __shared__ float lred[RT_TOK];
  int tid = threadIdx.x;
  int w = tid >> 6;   // wave = local token, 0..15
  int l = tid & 63;
  int tok0 = blockIdx.x * RT_TOK;
  int tok = tok0 + w;

  // stage pgmin: 1024 threads cover 64 grp x 16 tok; full-line coalesced
  {
    int grp = tid >> 4;
    int tk = tid & 15;
    pg[grp][tk] = pgmin[(size_t)grp * TOKENS + tok0 + tk];
  }
  if (tid < RT_TOK * DIM)
    zsh[tid >> 5][tid & 31] = hs[(size_t)tok0 * DIM + tid];
  __syncthreads();

  // z into registers (broadcast LDS reads, compile-time indices only)
  float zf[DIM];
#pragma unroll
  for (int j = 0; j < 8; j++) {
    float4 q = *(const float4*)&zsh[w][4 * j];
    zf[4 * j] = q.x; zf[4 * j + 1] = q.y;
    zf[4 * j + 2] = q.z; zf[4 * j + 3] = q.w;
  }
  float s0 = 0.f, s1 = 0.f, s2 = 0.f, s3 = 0.f;
#pragma unroll
  for (int j = 0; j < 8; j++) {
    s0 = fmaf(zf[4 * j], zf[4 * j], s0);
    s1 = fmaf(zf[4 * j + 1], zf[4 * j + 1], s1);
    s2 = fmaf(zf[4 * j + 2], zf[4 * j + 2], s2);
    s3 = fmaf(zf[4 * j + 3], zf[4 * j + 3], s3);
  }
  float sz = (s0 + s1) + (s2 + s3);
  float rz = 1.0f / sqrtf(sz + 1e-12f);
  float szn = sz * rz * rz;

  // candidate groups
  float v = pg[l][w];
  float m = v;
#pragma unroll
  for (int off = 1; off < 64; off <<= 1) m = fminf(m, __shfl_xor(m, off));
  unsigned long long mask = __ballot(v <= m + MARGIN);

  unsigned long long bkey = ~0ull;
  while (mask) {
    int grp = __ffsll(mask) - 1;
    mask &= mask - 1;
#pragma unroll
    for (int half = 0; half < 2; half++) {
      int c = grp * GSZ + half * 64 + l;
      const float4* ep = (const float4*)(emb + (size_t)c * DIM);
      float d0 = 0.f, d1 = 0.f, d2 = 0.f, d3 = 0.f;
#pragma unroll
      for (int j = 0; j < 8; j++) {
        float4 q = ep[j];
        d0 = fmaf(zf[4 * j], q.x, d0);
        d1 = fmaf(zf[4 * j + 1], q.y, d1);
        d2 = fmaf(zf[4 * j + 2], q.z, d2);
        d3 = fmaf(zf[4 * j + 3], q.w, d3);
      }
      float dot = (d0 + d1) + (d2 + d3);
      float se = seArr[c];
      float re = 1.0f / sqrtf(se + 1e-12f);
      float D = szn + se * re * re - 2.0f * dot * rz * re;
      // monotone total-order mapping of f32 (handles tiny negatives)
      unsigned ud = __float_as_uint(D);
      ud ^= (unsigned)((int)ud >> 31) | 0x80000000u;
      unsigned long long key = ((unsigned long long)ud << 32) | (unsigned)c;
      if (key < bkey) bkey = key;
    }
  }
  // 6-step u64 min reduce: exact dist order + smallest-index tie-break
#pragma unroll
  for (int off = 1; off < 64; off <<= 1) {
    unsigned long long o = __shfl_xor(bkey, off);
    bkey = (o < bkey) ? o : bkey;
  }
  int bestidx = (int)(unsigned)bkey;

  if (l == 0) out[(size_t)ZQ_ELEMS + tok] = (float)bestidx;

  // z_q + loss (lanes 0..31)
  int d = l & 31;
  float ev = emb[(size_t)bestidx * DIM + d];
  float reW = 1.0f / sqrtf(seArr[bestidx] + 1e-12f);
  float zq = ev * reW;
  float lp = 0.f;
  if (l < 32) {
    out[(size_t)tok * DIM + d] = zq;
    float hn = zsh[w][d] * rz;
    float diff = zq - hn;
    lp = diff * diff;
  }
#pragma unroll
  for (int off = 1; off < 32; off <<= 1) lp += __shfl_xor(lp, off);
  if (l == 0) lred[w] = lp;
  __syncthreads();
  if (tid == 0) {
    float b = 0.f;
#pragma unroll
    for (int i = 0; i < RT_TOK; i++) b += lred[i];
    atomicAdd(lossacc + (blockIdx.x & 127), b);
  }
}

// ---------------------------------------------------------------------------
// loss finalize: sum 128 partial slots, write both (identical) losses.
// ---------------------------------------------------------------------------
__global__ void loss_write_kernel(const float* __restrict__ lossacc,
                                  float* __restrict__ out) {
  int l = threadIdx.x;  // 64 threads
  float s = lossacc[l] + lossacc[l + 64];
#pragma unroll
  for (int off = 1; off < 64; off <<= 1) s += __shfl_xor(s, off);
  if (l == 0) {
    float v = s * (1.0f / (float)ZQ_ELEMS);
    out[ZQ_ELEMS + TOKENS] = v;
    out[ZQ_ELEMS + TOKENS + 1] = v;
  }
}

extern "C" void kernel_launch(void* const* d_in, const int* in_sizes, int n_in,
                              void* d_out, int out_size, void* d_ws,
                              size_t ws_size, hipStream_t stream) {
  const float* hs = (const float*)d_in[0];   // [32,1024,32]
  const float* emb = (const float*)d_in[1];  // [8192,32]
  float* out = (float*)d_out;
  char* ws = (char*)d_ws;

  short* cA = (short*)(ws);                        // 512 KB
  short* cB = (short*)(ws + 524288);               // 512 KB
  float* seArr = (float*)(ws + 1048576);           // 32 KB
  float* pgmin = (float*)(ws + 1081344);           // 8 MB: [64][32768]
  float* lossacc = (float*)(ws + 9469952);         // 512 B (128 slots)

  hipLaunchKernelGGL(prep_codes, dim3((KCODES * DIM) / 256), dim3(256), 0,
                     stream, emb, cA, cB, seArr);
  hipMemsetAsync(lossacc, 0, 512, stream);
  hipLaunchKernelGGL(screen_kernel, dim3(TOKENS / 256, NCHUNK), dim3(256), 0,
                     stream, hs, cA, cB, pgmin);
  hipLaunchKernelGGL(rescore_kernel, dim3(TOKENS / RT_TOK), dim3(1024), 0,
                     stream, hs, emb, seArr, pgmin, out, lossacc);
  hipLaunchKernelGGL(loss_write_kernel, dim3(1), dim3(64), 0, stream, lossacc,
                     out);
}

// Round 7
// 105.515 us; speedup vs baseline: 1.3674x; 1.3674x over previous
//
#include <hip/hip_runtime.h>
#include <math.h>

#define TOKENS 32768
#define KCODES 8192
#define DIM 32
#define NCHUNK 16
#define CPC 512                    // codes per chunk (per screen block)
#define GSZ 128                    // codes per stored-min group
#define NGROUPS 64                 // KCODES / GSZ
#define RT_TOK 16                  // tokens per rescore block (1 per wave)
#define ZQ_ELEMS (TOKENS * DIM)
#define MARGIN 1e-3f               // screen-unit margin (>> 2*eps_screen)

typedef __attribute__((ext_vector_type(8))) short short8v;  // 8 bf16
typedef __attribute__((ext_vector_type(4))) float f32x4;

// round-to-nearest-even float bits -> bf16 bits
__device__ inline unsigned rne16(unsigned u) {
  return (u + 0x7FFFu + ((u >> 16) & 1u)) >> 16;
}

// ---------------------------------------------------------------------------
// prep: per code row: raw sum(e^2) (f64 accum -> seF), normalized row ê;
// nsq = sum(ê^2) f32; embT4 = ê in block-transposed [d>>2][code][d&3] layout
// (rescore reads lane-contiguous float4); cA/cB = -ê split into 2 bf16
// terms in MFMA-A-fragment-linear layout for the screen kernel.
// ---------------------------------------------------------------------------
__global__ __launch_bounds__(256) void prep_codes(
    const float* __restrict__ emb, short* __restrict__ cA,
    short* __restrict__ cB, float* __restrict__ embT4,
    float* __restrict__ nsq, float* __restrict__ seF) {
  int gid = blockIdx.x * 256 + threadIdx.x;  // 0..262143
  int code = gid >> 5;
  int k = gid & 31;
  float v = emb[gid];
  double dv = (double)v;
  double ds = dv * dv;
#pragma unroll
  for (int off = 16; off > 0; off >>= 1) ds += __shfl_xor(ds, off, 32);
  if (k == 0) seF[code] = (float)ds;
  float r = 1.0f / sqrtf((float)ds + 1e-12f);
  float en = v * r;
  float sn = en * en;
#pragma unroll
  for (int off = 16; off > 0; off >>= 1) sn += __shfl_xor(sn, off, 32);
  if (k == 0) nsq[code] = sn;
  embT4[(size_t)((k >> 2) * KCODES + code) * 4 + (k & 3)] = en;

  float w = -en;
  unsigned ua = rne16(__float_as_uint(w));
  float fa = __uint_as_float(ua << 16);
  unsigned ub = rne16(__float_as_uint(w - fa));
  int tile = code >> 4;
  int lane = (code & 15) | ((k >> 3) << 4);
  int off = tile * 512 + lane * 8 + (k & 7);
  cA[off] = (short)ua;
  cB[off] = (short)ub;
}

// ---------------------------------------------------------------------------
// screen: 3-term MFMA of s = z . (-e_n) (raw z).  Block = 4 waves x 64
// tokens; grid = (128 token-blocks, 16 chunks).  No LDS, no barriers.
// Stores per-(group,token) min screen value; group = 128 codes.
// (unchanged from round 6)
// ---------------------------------------------------------------------------
__global__ __launch_bounds__(256) void screen_kernel(
    const float* __restrict__ hs, const short* __restrict__ cA,
    const short* __restrict__ cB, float* __restrict__ pgmin) {
  int tid = threadIdx.x;
  int l = tid & 63;
  int w = tid >> 6;
  int g = l >> 4;
  int c16 = l & 15;
  int gt0 = blockIdx.x * 16 + w * 4;  // first token-tile of this wave
  int chunk = blockIdx.y;

  // token-side B fragments: raw z, 2-term bf16 split
  short8v zA[4], zB[4];
#pragma unroll
  for (int tt = 0; tt < 4; tt++) {
    int tok = (gt0 + tt) * 16 + c16;
    const float4* hp4 = (const float4*)(hs + (size_t)tok * DIM + g * 8);
    float4 q0 = hp4[0];
    float4 q1 = hp4[1];
    float x[8] = {q0.x, q0.y, q0.z, q0.w, q1.x, q1.y, q1.z, q1.w};
#pragma unroll
    for (int j = 0; j < 8; j++) {
      unsigned ua = rne16(__float_as_uint(x[j]));
      float fa = __uint_as_float(ua << 16);
      unsigned ub = rne16(__float_as_uint(x[j] - fa));
      zA[tt][j] = (short)ua;
      zB[tt][j] = (short)ub;
    }
  }

  int tbase = chunk * (CPC / 16);  // 32 tiles per chunk

  for (int grp = 0; grp < CPC / GSZ; grp++) {  // 4 groups of 128 codes
    float gm[4] = {3.4e38f, 3.4e38f, 3.4e38f, 3.4e38f};
#pragma unroll
    for (int ct = 0; ct < GSZ / 16; ct++) {  // 8 code-tiles
      int tile = tbase + grp * (GSZ / 16) + ct;
      short8v aA = *((const short8v*)(cA + (size_t)tile * 512) + l);
      short8v aB = *((const short8v*)(cB + (size_t)tile * 512) + l);
#pragma unroll
      for (int tt = 0; tt < 4; tt++) {
        f32x4 acc = {};
        acc = __builtin_amdgcn_mfma_f32_16x16x32_bf16(aA, zA[tt], acc, 0, 0, 0);
        acc = __builtin_amdgcn_mfma_f32_16x16x32_bf16(aA, zB[tt], acc, 0, 0, 0);
        acc = __builtin_amdgcn_mfma_f32_16x16x32_bf16(aB, zA[tt], acc, 0, 0, 0);
        float m = fminf(fminf(acc[0], acc[1]), fminf(acc[2], acc[3]));
        gm[tt] = fminf(gm[tt], m);
      }
    }
    int gidx = (chunk * (CPC / GSZ) + grp);
#pragma unroll
    for (int tt = 0; tt < 4; tt++) {
      float v = gm[tt];
      v = fminf(v, __shfl_xor(v, 16));
      v = fminf(v, __shfl_xor(v, 32));
      if (l < 16) {
        int tok = (gt0 + tt) * 16 + c16;
        pgmin[(size_t)gidx * TOKENS + tok] = v;
      }
    }
  }
}

// ---------------------------------------------------------------------------
// rescore: block = 1024 threads = 16 waves = 16 tokens (one per wave).
// Candidate-distance loop reads the NORMALIZED transposed codebook embT4 in
// fully-coalesced float4 wave-loads (no 64-line gathers) and uses
// precomputed nsq (no per-candidate rsqrt):
//   D = szn + nsq[c] - 2*rz*dot(z, ê_c)
// Argmin via packed (monotone-f32-bits, idx) u64 min reduce (exact value
// order + smallest-index tie-break).  Fused z_q gather (raw emb row,
// coalesced) /normalize, index write, loss partial (one atomic per block).
// ---------------------------------------------------------------------------
__global__ __launch_bounds__(1024) void rescore_kernel(
    const float* __restrict__ hs, const float* __restrict__ emb,
    const float* __restrict__ embT4, const float* __restrict__ nsq,
    const float* __restrict__ seF, const float* __restrict__ pgmin,
    float* __restrict__ out, float* __restrict__ lossacc) {
  __shared__ float pg[NGROUPS][RT_TOK + 1];  // [grp][tok], padded
  __shared__ float zsh[RT_TOK][DIM];
  __shared__ float lred[RT_TOK];
  int tid = threadIdx.x;
  int w = tid >> 6;   // wave = local token, 0..15
  int l = tid & 63;
  int tok0 = blockIdx.x * RT_TOK;
  int tok = tok0 + w;

  // stage pgmin: 1024 threads cover 64 grp x 16 tok; full-line coalesced
  {
    int grp = tid >> 4;
    int tk = tid & 15;
    pg[grp][tk] = pgmin[(size_t)grp * TOKENS + tok0 + tk];
  }
  if (tid < RT_TOK * DIM)
    zsh[tid >> 5][tid & 31] = hs[(size_t)tok0 * DIM + tid];
  __syncthreads();

  // z into registers (broadcast LDS reads, compile-time indices only)
  float zf[DIM];
#pragma unroll
  for (int j = 0; j < 8; j++) {
    float4 q = *(const float4*)&zsh[w][4 * j];
    zf[4 * j] = q.x; zf[4 * j + 1] = q.y;
    zf[4 * j + 2] = q.z; zf[4 * j + 3] = q.w;
  }
  float s0 = 0.f, s1 = 0.f, s2 = 0.f, s3 = 0.f;
#pragma unroll
  for (int j = 0; j < 8; j++) {
    s0 = fmaf(zf[4 * j], zf[4 * j], s0);
    s1 = fmaf(zf[4 * j + 1], zf[4 * j + 1], s1);
    s2 = fmaf(zf[4 * j + 2], zf[4 * j + 2], s2);
    s3 = fmaf(zf[4 * j + 3], zf[4 * j + 3], s3);
  }
  float sz = (s0 + s1) + (s2 + s3);
  float rz = 1.0f / sqrtf(sz + 1e-12f);
  float szn = sz * rz * rz;
  float n2rz = -2.0f * rz;

  // candidate groups
  float v = pg[l][w];
  float m = v;
#pragma unroll
  for (int off = 1; off < 64; off <<= 1) m = fminf(m, __shfl_xor(m, off));
  unsigned long long mask = __ballot(v <= m + MARGIN);

  unsigned long long bkey = ~0ull;
  const float4* tp = (const float4*)embT4;  // [8][KCODES] of float4
  while (mask) {
    int grp = __ffsll(mask) - 1;
    mask &= mask - 1;
#pragma unroll
    for (int half = 0; half < 2; half++) {
      int c = grp * GSZ + half * 64 + l;
      float d0 = 0.f, d1 = 0.f, d2 = 0.f, d3 = 0.f;
#pragma unroll
      for (int d4 = 0; d4 < 8; d4++) {
        float4 q = tp[(size_t)d4 * KCODES + c];  // lane-contiguous
        d0 = fmaf(zf[4 * d4], q.x, d0);
        d1 = fmaf(zf[4 * d4 + 1], q.y, d1);
        d2 = fmaf(zf[4 * d4 + 2], q.z, d2);
        d3 = fmaf(zf[4 * d4 + 3], q.w, d3);
      }
      float dot = (d0 + d1) + (d2 + d3);
      float D = fmaf(n2rz, dot, szn + nsq[c]);
      // monotone total-order mapping of f32 (handles tiny negatives)
      unsigned ud = __float_as_uint(D);
      ud ^= (unsigned)((int)ud >> 31) | 0x80000000u;
      unsigned long long key = ((unsigned long long)ud << 32) | (unsigned)c;
      if (key < bkey) bkey = key;
    }
  }
  // 6-step u64 min reduce: exact dist order + smallest-index tie-break
#pragma unroll
  for (int off = 1; off < 64; off <<= 1) {
    unsigned long long o = __shfl_xor(bkey, off);
    bkey = (o < bkey) ? o : bkey;
  }
  int bestidx = (int)(unsigned)bkey;

  if (l == 0) out[(size_t)ZQ_ELEMS + tok] = (float)bestidx;

  // z_q + loss (lanes 0..31): raw emb row (coalesced), one rsqrt per token
  int d = l & 31;
  float ev = emb[(size_t)bestidx * DIM + d];
  float reW = 1.0f / sqrtf(seF[bestidx] + 1e-12f);
  float zq = ev * reW;
  float lp = 0.f;
  if (l < 32) {
    out[(size_t)tok * DIM + d] = zq;
    float hn = zsh[w][d] * rz;
    float diff = zq - hn;
    lp = diff * diff;
  }
#pragma unroll
  for (int off = 1; off < 32; off <<= 1) lp += __shfl_xor(lp, off);
  if (l == 0) lred[w] = lp;
  __syncthreads();
  if (tid == 0) {
    float b = 0.f;
#pragma unroll
    for (int i = 0; i < RT_TOK; i++) b += lred[i];
    atomicAdd(lossacc + (blockIdx.x & 127), b);
  }
}

// ---------------------------------------------------------------------------
// loss finalize: sum 128 partial slots, write both (identical) losses.
// ---------------------------------------------------------------------------
__global__ void loss_write_kernel(const float* __restrict__ lossacc,
                                  float* __restrict__ out) {
  int l = threadIdx.x;  // 64 threads
  float s = lossacc[l] + lossacc[l + 64];
#pragma unroll
  for (int off = 1; off < 64; off <<= 1) s += __shfl_xor(s, off);
  if (l == 0) {
    float v = s * (1.0f / (float)ZQ_ELEMS);
    out[ZQ_ELEMS + TOKENS] = v;
    out[ZQ_ELEMS + TOKENS + 1] = v;
  }
}

extern "C" void kernel_launch(void* const* d_in, const int* in_sizes, int n_in,
                              void* d_out, int out_size, void* d_ws,
                              size_t ws_size, hipStream_t stream) {
  const float* hs = (const float*)d_in[0];   // [32,1024,32]
  const float* emb = (const float*)d_in[1];  // [8192,32]
  float* out = (float*)d_out;
  char* ws = (char*)d_ws;

  short* cA = (short*)(ws);                        // 512 KB @ 0
  short* cB = (short*)(ws + 524288);               // 512 KB
  float* embT4 = (float*)(ws + 1048576);           // 1 MB  (normalized, T4)
  float* nsq = (float*)(ws + 2097152);             // 32 KB (sum ê²)
  float* seF = (float*)(ws + 2129920);             // 32 KB (raw sum e²)
  float* pgmin = (float*)(ws + 2162688);           // 8 MB: [64][32768]
  float* lossacc = (float*)(ws + 10551296);        // 512 B (128 slots)

  hipLaunchKernelGGL(prep_codes, dim3((KCODES * DIM) / 256), dim3(256), 0,
                     stream, emb, cA, cB, embT4, nsq, seF);
  hipMemsetAsync(lossacc, 0, 512, stream);
  hipLaunchKernelGGL(screen_kernel, dim3(TOKENS / 256, NCHUNK), dim3(256), 0,
                     stream, hs, cA, cB, pgmin);
  hipLaunchKernelGGL(rescore_kernel, dim3(TOKENS / RT_TOK), dim3(1024), 0,
                     stream, hs, emb, embT4, nsq, seF, pgmin, out, lossacc);
  hipLaunchKernelGGL(loss_write_kernel, dim3(1), dim3(64), 0, stream, lossacc,
                     out);
}